// Round 2
// baseline (740.376 us; speedup 1.0000x reference)
//
#include <hip/hip_runtime.h>

// MixProp on MI355X — closed-form hop-matrix pipeline + VGPR-resident final.
//
// Key identity: the hop recurrence H_k = beta*X + P·H_{k-1} with
//   P = (1-beta) * rownorm(A+I)
// is linear in X, so H_k = M_k · X over the node dim, where
//   M_1     = beta*I + P
//   M_{k+1} = beta*I + M_k * P      (P commutes with any polynomial of P)
// The three hops are INDEPENDENT 512x512-matrix applications of X.
//
// Pipeline (intermediates f16 in ws):
//   norm_A   : M1 = beta*I + P  and  Pt = P^T                    [512][512]
//   small_mm : M2 = M1*P + beta*I ; M3 = M2*P + beta*I   (MFMA, B = Pt)
//   prep_X   : Xt[l][w] f16 per (b,c) plane (hop B-operand)
//   hop_mfma : Hn_g[v][l] (MFMA f16, g folded into grid.z)
//   final    : out = bias + W·[X,H1,H2,H3]  (v_dot2_f32_f16 conv)
//
// final_kernel round-2 fix: previous version kept 64 live fp32 accumulators;
// at the compiler's default occupancy budget they landed in AGPRs
// (VGPR_Count=36 in rocprof, no scratch) -> v_accvgpr ping-pong around every
// fdot2 made the kernel VALU-issue-bound (233us vs ~70us roofline). Now: two
// passes of 32 output channels (acc[32] stays in arch VGPRs) + explicit
// __launch_bounds__(256,4) (128-VGPR unified budget). Second pass re-reads
// X/H from L2 (80KB/block working set, L2-resident) so HBM FETCH unchanged.

#define NODES 512
#define SEQL  256
#define CIN   32
#define COUT  64
#define NB    8
#define PLANE (NODES * SEQL)   // 131072
#define BETA_F 0.05f

typedef _Float16 f16x8 __attribute__((ext_vector_type(8)));
typedef _Float16 f16x2 __attribute__((ext_vector_type(2)));
typedef float    f32x4 __attribute__((ext_vector_type(4)));

typedef const unsigned int __attribute__((address_space(1)))* gptr_t;
typedef unsigned int __attribute__((address_space(3)))* lptr_t;

__device__ __forceinline__ void gload16(const void* g, void* l) {
    __builtin_amdgcn_global_load_lds((gptr_t)g, (lptr_t)l, 16, 0, 0);
}

__device__ __forceinline__ unsigned short f2h(float f) {
    _Float16 h = (_Float16)f;
    return __builtin_bit_cast(unsigned short, h);
}

// ---------------------------------------------------------------------------
// P = (1-beta)*(A+I)/rowsum.  Writes M1 = beta*I + P  and  Pt = P^T (f16).
__global__ __launch_bounds__(256) void norm_A_kernel(const float* __restrict__ A,
                                                     _Float16* __restrict__ M1,
                                                     _Float16* __restrict__ Pt) {
    const int v = blockIdx.x;
    const int t = threadIdx.x;
    __shared__ float red[256];
    float s = 0.f;
    for (int w = t; w < NODES; w += 256)
        s += A[v * NODES + w] + (w == v ? 1.f : 0.f);
    red[t] = s;
    __syncthreads();
    for (int off = 128; off > 0; off >>= 1) {
        if (t < off) red[t] += red[t + off];
        __syncthreads();
    }
    const float inv = (1.f - BETA_F) / red[0];
    for (int w = t; w < NODES; w += 256) {
        const float p = (A[v * NODES + w] + (w == v ? 1.f : 0.f)) * inv;
        M1[v * NODES + w] = (_Float16)(p + (w == v ? BETA_F : 0.f));
        Pt[w * NODES + v] = (_Float16)p;   // tiny scatter: 512x512 only
    }
}

// ---------------------------------------------------------------------------
// Wt[c][o] fp32 (for the fp32-X group) and Wp[pair][o] packed f16x2
__global__ __launch_bounds__(256) void prep_W_kernel(const float* __restrict__ W,
                                                     float* __restrict__ Wt,
                                                     unsigned int* __restrict__ Wp) {
    const int i = blockIdx.x * 256 + threadIdx.x;   // 0..8191
    const int o = i >> 7, c = i & 127;
    Wt[c * COUT + o] = W[i];
    if (i < 4096) {
        const int p = i >> 6, oo = i & 63;
        Wp[i] = (unsigned)f2h(W[oo * 128 + 2 * p]) |
                ((unsigned)f2h(W[oo * 128 + 2 * p + 1]) << 16);
    }
}

// ---------------------------------------------------------------------------
// Xt[(b,c)][l][v] f16 from X fp32 [(b,c)][v][l].  64x64 LDS tile transpose.
// grid: (l-tiles=4, v-tiles=8, chunk=256)
__global__ __launch_bounds__(256) void prep_X_kernel(const float* __restrict__ X,
                                                     unsigned short* __restrict__ Xt) {
    const int l0 = blockIdx.x * 64, v0 = blockIdx.y * 64;
    const size_t coff = (size_t)blockIdx.z * PLANE;
    __shared__ unsigned short t[64][66];   // [l][v], pad 66: conflict-light
    const int rr = threadIdx.x >> 4;
    const int cc = (threadIdx.x & 15) * 4;
#pragma unroll
    for (int rep = 0; rep < 4; ++rep) {
        const int vl = rep * 16 + rr;
        const float4 f = *(const float4*)(X + coff + (size_t)(v0 + vl) * SEQL + l0 + cc);
        t[cc + 0][vl] = f2h(f.x);
        t[cc + 1][vl] = f2h(f.y);
        t[cc + 2][vl] = f2h(f.z);
        t[cc + 3][vl] = f2h(f.w);
    }
    __syncthreads();
#pragma unroll
    for (int rep = 0; rep < 4; ++rep) {
        const int ll = rep * 16 + rr;
        ushort4 d;
        d.x = t[ll][cc + 0]; d.y = t[ll][cc + 1];
        d.z = t[ll][cc + 2]; d.w = t[ll][cc + 3];
        *(ushort4*)(Xt + coff + (size_t)(l0 + ll) * NODES + v0 + cc) = d;
    }
}

// ---------------------------------------------------------------------------
// Mout[v][w] = sum_u Min[v][u]*Pt[w][u] + beta*I  (i.e. Min*P + beta*I)
// 512x512x512, one 128x128 tile per block, grid (4,4).
__global__ __launch_bounds__(256) void small_mm_kernel(
    const _Float16* __restrict__ Min,
    const _Float16* __restrict__ Pt,
    _Float16* __restrict__ Mout)
{
    __shared__ _Float16 Asl[128 * 64];
    __shared__ _Float16 Bsl[128 * 64];

    const int tid  = threadIdx.x;
    const int wave = tid >> 6;
    const int lane = tid & 63;
    const int n0 = blockIdx.x * 128;     // w
    const int m0 = blockIdx.y * 128;     // v

    const int wm = (wave >> 1) * 64;
    const int wn = (wave & 1) * 64;
    const int lane15 = lane & 15;
    const int quad = lane >> 4;
    const int srow = lane >> 3;
    const int spos = lane & 7;

    f32x4 acc[4][4] = {};

    for (int kk = 0; kk < 8; ++kk) {
        const int k0 = kk * 64;
#pragma unroll
        for (int j = 0; j < 4; ++j) {
            const int r = wave * 32 + j * 8 + srow;
            const int gc = k0 + ((spos ^ (r & 7)) << 3);
            gload16(Min + (size_t)(m0 + r) * NODES + gc, &Asl[(wave * 32 + j * 8) * 64]);
            gload16(Pt  + (size_t)(n0 + r) * NODES + gc, &Bsl[(wave * 32 + j * 8) * 64]);
        }
        __syncthreads();
#pragma unroll
        for (int ks = 0; ks < 2; ++ks) {
            f16x8 af[4], bf[4];
#pragma unroll
            for (int mt = 0; mt < 4; ++mt) {
                const int m = wm + mt * 16 + lane15;
                const int pos = (ks * 4 + quad) ^ (m & 7);
                af[mt] = *(const f16x8*)&Asl[m * 64 + pos * 8];
            }
#pragma unroll
            for (int nt = 0; nt < 4; ++nt) {
                const int n = wn + nt * 16 + lane15;
                const int pos = (ks * 4 + quad) ^ (n & 7);
                bf[nt] = *(const f16x8*)&Bsl[n * 64 + pos * 8];
            }
#pragma unroll
            for (int mt = 0; mt < 4; ++mt)
#pragma unroll
                for (int nt = 0; nt < 4; ++nt)
                    acc[mt][nt] = __builtin_amdgcn_mfma_f32_16x16x32_f16(
                        af[mt], bf[nt], acc[mt][nt], 0, 0, 0);
        }
        __syncthreads();
    }

#pragma unroll
    for (int mt = 0; mt < 4; ++mt) {
#pragma unroll
        for (int nt = 0; nt < 4; ++nt) {
            const int v = m0 + wm + mt * 16 + quad * 4;
            const int w = n0 + wn + nt * 16 + lane15;
#pragma unroll
            for (int r = 0; r < 4; ++r)
                Mout[(size_t)(v + r) * NODES + w] =
                    (_Float16)(acc[mt][nt][r] + ((v + r) == w ? BETA_F : 0.f));
        }
    }
}

// ---------------------------------------------------------------------------
// Hn_g[v][l] = sum_w M_g[v][w] * Xt[l][w]    (beta*X folded into M_g's diag)
// Block: 128(v) x 128(l) tile, 4 waves of 64x64, BK=64, mfma f32_16x16x32_f16.
// grid: (l-tiles=2, v-tiles=4, z = 3*chunk + g) — g fastest so the three
// GEMMs sharing the same Xt chunk run back-to-back (L2/L3 reuse).
__global__ __launch_bounds__(256) void hop_mfma_kernel(
    const _Float16* __restrict__ M1,
    const _Float16* __restrict__ M2,
    const _Float16* __restrict__ M3,
    const _Float16* __restrict__ Xt,     // [chunk][l=256][w=512]
    _Float16* __restrict__ H1,           // [chunk][v=512][l=256]
    _Float16* __restrict__ H2,
    _Float16* __restrict__ H3)
{
    __shared__ _Float16 Asl[128 * 64];   // rows m=v, BK=64 w
    __shared__ _Float16 Bsl[128 * 64];   // rows n=l, BK=64 w

    const int z = blockIdx.z;
    const int chunk = z / 3;
    const int g = z - 3 * chunk;
    const _Float16* __restrict__ M = (g == 0) ? M1 : (g == 1) ? M2 : M3;
    _Float16* __restrict__ H = (g == 0) ? H1 : (g == 1) ? H2 : H3;

    const int tid  = threadIdx.x;
    const int wave = tid >> 6;
    const int lane = tid & 63;
    const int n0 = blockIdx.x * 128;     // l
    const int m0 = blockIdx.y * 128;     // v
    const size_t coff = (size_t)chunk * PLANE;
    const _Float16* Bsrc = Xt + coff;

    const int wm = (wave >> 1) * 64;
    const int wn = (wave & 1) * 64;
    const int lane15 = lane & 15;
    const int quad = lane >> 4;
    const int srow = lane >> 3;          // staging: row within 8-row group
    const int spos = lane & 7;           // staging: 16B chunk slot

    f32x4 acc[4][4] = {};

    for (int kk = 0; kk < 8; ++kk) {
        const int k0 = kk * 64;
        // --- stage A (M_g rows v) and B (Xt rows l), XOR-swizzled source ---
#pragma unroll
        for (int j = 0; j < 4; ++j) {
            const int r = wave * 32 + j * 8 + srow;            // tile-local row
            const int gc = k0 + ((spos ^ (r & 7)) << 3);       // swizzled global col
            gload16(M    + (size_t)(m0 + r) * NODES + gc, &Asl[(wave * 32 + j * 8) * 64]);
            gload16(Bsrc + (size_t)(n0 + r) * NODES + gc, &Bsl[(wave * 32 + j * 8) * 64]);
        }
        __syncthreads();
        // --- compute ---
#pragma unroll
        for (int ks = 0; ks < 2; ++ks) {
            f16x8 af[4], bf[4];
#pragma unroll
            for (int mt = 0; mt < 4; ++mt) {
                const int m = wm + mt * 16 + lane15;
                const int pos = (ks * 4 + quad) ^ (m & 7);
                af[mt] = *(const f16x8*)&Asl[m * 64 + pos * 8];
            }
#pragma unroll
            for (int nt = 0; nt < 4; ++nt) {
                const int n = wn + nt * 16 + lane15;
                const int pos = (ks * 4 + quad) ^ (n & 7);
                bf[nt] = *(const f16x8*)&Bsl[n * 64 + pos * 8];
            }
#pragma unroll
            for (int mt = 0; mt < 4; ++mt)
#pragma unroll
                for (int nt = 0; nt < 4; ++nt)
                    acc[mt][nt] = __builtin_amdgcn_mfma_f32_16x16x32_f16(
                        af[mt], bf[nt], acc[mt][nt], 0, 0, 0);
        }
        __syncthreads();
    }

    // --- epilogue: D rows v (quad*4+r), cols l (lane15); natural layout ---
#pragma unroll
    for (int mt = 0; mt < 4; ++mt) {
#pragma unroll
        for (int nt = 0; nt < 4; ++nt) {
            const int v = m0 + wm + mt * 16 + quad * 4;
            const int l = n0 + wn + nt * 16 + lane15;
            const size_t base = coff + (size_t)v * SEQL + l;
#pragma unroll
            for (int r = 0; r < 4; ++r)
                H[base + (size_t)r * SEQL] = (_Float16)acc[mt][nt][r];
        }
    }
}

// ---------------------------------------------------------------------------
// out[b,o,v,l] = bias[o] + sum_c Wt[c][o]*X[c] (fp32) + dot2 pairs over H1..H3
// grid: (v=512, b=8), thread = l.
// Two passes of 32 output channels so acc[] stays in arch VGPRs (no AGPR
// ping-pong); __launch_bounds__(256,4) gives a 128-VGPR unified budget.
// Second pass re-reads X/H from L2 (80KB/block working set) — no extra HBM.
__global__ __launch_bounds__(256, 4) void final_kernel(
    const float* __restrict__ X,
    const _Float16* __restrict__ H1,
    const _Float16* __restrict__ H2,
    const _Float16* __restrict__ H3,
    const float* __restrict__ Wt,
    const unsigned int* __restrict__ Wp,
    const float* __restrict__ bias,
    float* __restrict__ out)
{
    const int v = blockIdx.x, b = blockIdx.y, l = threadIdx.x;
    const size_t vl = (size_t)v * SEQL + l;
    const _Float16* Hs[3] = {H1, H2, H3};

#pragma unroll 1
    for (int half = 0; half < 2; ++half) {
        const int o0 = half * 32;
        float acc[32];
#pragma unroll
        for (int o = 0; o < 32; ++o) acc[o] = bias[o0 + o];

        // group 0: original fp32 X, plain fmac
        {
            const float* P = X + (size_t)b * CIN * PLANE + vl;
            for (int c = 0; c < CIN; ++c) {
                const float x = P[(size_t)c * PLANE];
                const float* wr = Wt + c * COUT + o0;
#pragma unroll
                for (int o = 0; o < 32; ++o) acc[o] += wr[o] * x;
            }
        }
        // groups 1..3: f16 hop planes, v_dot2_f32_f16 over channel pairs
#pragma unroll
        for (int g = 0; g < 3; ++g) {
            const _Float16* P = Hs[g] + (size_t)b * CIN * PLANE + vl;
            for (int cp = 0; cp < 16; ++cp) {
                const _Float16 h0 = P[(size_t)(2 * cp) * PLANE];
                const _Float16 h1 = P[(size_t)(2 * cp + 1) * PLANE];
                const f16x2 hp = {h0, h1};
                const unsigned int* wr = Wp + ((g + 1) * 16 + cp) * COUT + o0;
#pragma unroll
                for (int o = 0; o < 32; ++o)
                    acc[o] = __builtin_amdgcn_fdot2(hp, __builtin_bit_cast(f16x2, wr[o]),
                                                    acc[o], false);
            }
        }
        float* O = out + (size_t)b * COUT * PLANE + (size_t)o0 * PLANE + vl;
#pragma unroll
        for (int o = 0; o < 32; ++o) O[(size_t)o * PLANE] = acc[o];
    }
}

// ---------------------------------------------------------------------------
extern "C" void kernel_launch(void* const* d_in, const int* in_sizes, int n_in,
                              void* d_out, int out_size, void* d_ws, size_t ws_size,
                              hipStream_t stream) {
    (void)in_sizes; (void)n_in; (void)out_size; (void)ws_size;
    const float* X    = (const float*)d_in[0];
    const float* A    = (const float*)d_in[1];
    const float* W    = (const float*)d_in[2];
    const float* bias = (const float*)d_in[3];
    float* out = (float*)d_out;
    char* w = (char*)d_ws;

    // ws layout (1 GiB available; we use 272 MiB)
    const size_t MB = 1ull << 20;
    float*        Wt  = (float*)(w);                     // 32 KB
    unsigned int* Wp  = (unsigned int*)(w + 64 * 1024);  // 16 KB
    _Float16*     M1  = (_Float16*)(w + 1 * MB);         // 512 KB each
    _Float16*     M2  = (_Float16*)(w + 2 * MB);
    _Float16*     M3  = (_Float16*)(w + 3 * MB);
    _Float16*     Pt  = (_Float16*)(w + 4 * MB);
    _Float16*     Xt  = (_Float16*)(w + 16 * MB);        // 64 MB
    _Float16*     Hn1 = (_Float16*)(w + 80 * MB);        // 64 MB each
    _Float16*     Hn2 = (_Float16*)(w + 144 * MB);
    _Float16*     Hn3 = (_Float16*)(w + 208 * MB);

    norm_A_kernel<<<dim3(NODES), dim3(256), 0, stream>>>(A, M1, Pt);
    prep_W_kernel<<<dim3(32), dim3(256), 0, stream>>>(W, Wt, Wp);
    prep_X_kernel<<<dim3(4, 8, 256), dim3(256), 0, stream>>>(X, (unsigned short*)Xt);

    // hop matrices: M2 = M1*P + beta*I ; M3 = M2*P + beta*I
    small_mm_kernel<<<dim3(4, 4), dim3(256), 0, stream>>>(M1, Pt, M2);
    small_mm_kernel<<<dim3(4, 4), dim3(256), 0, stream>>>(M2, Pt, M3);

    // three independent hop GEMMs in one dispatch (g = z % 3)
    hop_mfma_kernel<<<dim3(2, 4, 768), dim3(256), 0, stream>>>(
        M1, M2, M3, Xt, Hn1, Hn2, Hn3);

    final_kernel<<<dim3(NODES, NB), dim3(256), 0, stream>>>(X, Hn1, Hn2, Hn3, Wt, Wp, bias, out);
}

// Round 3
// 697.084 us; speedup vs baseline: 1.0621x; 1.0621x over previous
//
#include <hip/hip_runtime.h>

// MixProp on MI355X — round 3: hop GEMM re-tiled (256x128, XCD-grouped) +
// all-f16 final.
//
// Closed-form hops: H_k = M_k · X (over nodes), M1 = beta*I + P,
// M_{k+1} = beta*I + M_k*P, P = (1-beta)*rownorm(A+I).
//
// Round-3 changes (profile: hop_mfma ~390us was the real #1, final 233us #2):
//  * hop_mfma: one flat GEMM D[v][n=(chunk,l)] = M_g[v][w]·Xt[n][w],
//    M=512, N=65536, K=512. Tile 256(v) x 128(n), 8 waves, BK=64.
//    1-D grid with explicit decode: f&7 = XCD slot, so all 12 blocks that
//    share one 256KB Xt chunk land on the SAME XCD -> B-panel re-reads hit
//    that XCD's L2 instead of bouncing off L3 (previously 4 vtiles x 3 g
//    re-read Xt from round-robin XCDs).
//  * final: one-pass acc[64] (round-1 structure; round-2's o-split doubled
//    FETCH and lost), all four groups via v_dot2_f32_f16. prep_X now also
//    emits Xc = f16(X) planes so group 0 is uniform with the hop groups
//    (fewer MAC issues, half the X fetch).

#define NODES 512
#define SEQL  256
#define CIN   32
#define COUT  64
#define NB    8
#define PLANE (NODES * SEQL)   // 131072
#define BETA_F 0.05f

typedef _Float16 f16x8 __attribute__((ext_vector_type(8)));
typedef _Float16 f16x2 __attribute__((ext_vector_type(2)));
typedef float    f32x4 __attribute__((ext_vector_type(4)));

typedef const unsigned int __attribute__((address_space(1)))* gptr_t;
typedef unsigned int __attribute__((address_space(3)))* lptr_t;

__device__ __forceinline__ void gload16(const void* g, void* l) {
    __builtin_amdgcn_global_load_lds((gptr_t)g, (lptr_t)l, 16, 0, 0);
}

__device__ __forceinline__ unsigned short f2h(float f) {
    _Float16 h = (_Float16)f;
    return __builtin_bit_cast(unsigned short, h);
}

// ---------------------------------------------------------------------------
// P = (1-beta)*(A+I)/rowsum.  Writes M1 = beta*I + P  and  Pt = P^T (f16).
__global__ __launch_bounds__(256) void norm_A_kernel(const float* __restrict__ A,
                                                     _Float16* __restrict__ M1,
                                                     _Float16* __restrict__ Pt) {
    const int v = blockIdx.x;
    const int t = threadIdx.x;
    __shared__ float red[256];
    float s = 0.f;
    for (int w = t; w < NODES; w += 256)
        s += A[v * NODES + w] + (w == v ? 1.f : 0.f);
    red[t] = s;
    __syncthreads();
    for (int off = 128; off > 0; off >>= 1) {
        if (t < off) red[t] += red[t + off];
        __syncthreads();
    }
    const float inv = (1.f - BETA_F) / red[0];
    for (int w = t; w < NODES; w += 256) {
        const float p = (A[v * NODES + w] + (w == v ? 1.f : 0.f)) * inv;
        M1[v * NODES + w] = (_Float16)(p + (w == v ? BETA_F : 0.f));
        Pt[w * NODES + v] = (_Float16)p;   // tiny scatter: 512x512 only
    }
}

// ---------------------------------------------------------------------------
// Wp[pair][o] packed f16x2 for all 64 channel-pairs (128 channels).
__global__ __launch_bounds__(256) void prep_W_kernel(const float* __restrict__ W,
                                                     unsigned int* __restrict__ Wp) {
    const int i = blockIdx.x * 256 + threadIdx.x;   // 0..4095
    const int p = i >> 6, oo = i & 63;
    Wp[p * COUT + oo] = (unsigned)f2h(W[oo * 128 + 2 * p]) |
                        ((unsigned)f2h(W[oo * 128 + 2 * p + 1]) << 16);
}

// ---------------------------------------------------------------------------
// Xt[(b,c)][l][v] f16 (hop B-operand) and Xc[(b,c)][v][l] f16 (final group 0)
// from X fp32 [(b,c)][v][l].  64x64 LDS tile transpose.
// grid: (l-tiles=4, v-tiles=8, chunk=256)
__global__ __launch_bounds__(256) void prep_X_kernel(const float* __restrict__ X,
                                                     unsigned short* __restrict__ Xt,
                                                     unsigned short* __restrict__ Xc) {
    const int l0 = blockIdx.x * 64, v0 = blockIdx.y * 64;
    const size_t coff = (size_t)blockIdx.z * PLANE;
    __shared__ unsigned short t[64][66];   // [l][v], pad 66: conflict-light
    const int rr = threadIdx.x >> 4;
    const int cc = (threadIdx.x & 15) * 4;
#pragma unroll
    for (int rep = 0; rep < 4; ++rep) {
        const int vl = rep * 16 + rr;
        const float4 f = *(const float4*)(X + coff + (size_t)(v0 + vl) * SEQL + l0 + cc);
        ushort4 h;
        h.x = f2h(f.x); h.y = f2h(f.y); h.z = f2h(f.z); h.w = f2h(f.w);
        t[cc + 0][vl] = h.x;
        t[cc + 1][vl] = h.y;
        t[cc + 2][vl] = h.z;
        t[cc + 3][vl] = h.w;
        // natural-layout f16 copy for final_kernel (coalesced 8B stores)
        *(ushort4*)(Xc + coff + (size_t)(v0 + vl) * SEQL + l0 + cc) = h;
    }
    __syncthreads();
#pragma unroll
    for (int rep = 0; rep < 4; ++rep) {
        const int ll = rep * 16 + rr;
        ushort4 d;
        d.x = t[ll][cc + 0]; d.y = t[ll][cc + 1];
        d.z = t[ll][cc + 2]; d.w = t[ll][cc + 3];
        *(ushort4*)(Xt + coff + (size_t)(l0 + ll) * NODES + v0 + cc) = d;
    }
}

// ---------------------------------------------------------------------------
// Mout[v][w] = sum_u Min[v][u]*Pt[w][u] + beta*I  (i.e. Min*P + beta*I)
// 512x512x512, one 128x128 tile per block, grid (4,4).  4 waves.
__global__ __launch_bounds__(256) void small_mm_kernel(
    const _Float16* __restrict__ Min,
    const _Float16* __restrict__ Pt,
    _Float16* __restrict__ Mout)
{
    __shared__ _Float16 Asl[128 * 64];
    __shared__ _Float16 Bsl[128 * 64];

    const int tid  = threadIdx.x;
    const int wave = tid >> 6;
    const int lane = tid & 63;
    const int n0 = blockIdx.x * 128;     // w
    const int m0 = blockIdx.y * 128;     // v

    const int wm = (wave >> 1) * 64;
    const int wn = (wave & 1) * 64;
    const int lane15 = lane & 15;
    const int quad = lane >> 4;
    const int srow = lane >> 3;
    const int spos = lane & 7;

    f32x4 acc[4][4] = {};

    for (int kk = 0; kk < 8; ++kk) {
        const int k0 = kk * 64;
#pragma unroll
        for (int j = 0; j < 4; ++j) {
            const int r = wave * 32 + j * 8 + srow;
            const int gc = k0 + ((spos ^ (r & 7)) << 3);
            gload16(Min + (size_t)(m0 + r) * NODES + gc, &Asl[(wave * 32 + j * 8) * 64]);
            gload16(Pt  + (size_t)(n0 + r) * NODES + gc, &Bsl[(wave * 32 + j * 8) * 64]);
        }
        __syncthreads();
#pragma unroll
        for (int ks = 0; ks < 2; ++ks) {
            f16x8 af[4], bf[4];
#pragma unroll
            for (int mt = 0; mt < 4; ++mt) {
                const int m = wm + mt * 16 + lane15;
                const int pos = (ks * 4 + quad) ^ (m & 7);
                af[mt] = *(const f16x8*)&Asl[m * 64 + pos * 8];
            }
#pragma unroll
            for (int nt = 0; nt < 4; ++nt) {
                const int n = wn + nt * 16 + lane15;
                const int pos = (ks * 4 + quad) ^ (n & 7);
                bf[nt] = *(const f16x8*)&Bsl[n * 64 + pos * 8];
            }
#pragma unroll
            for (int mt = 0; mt < 4; ++mt)
#pragma unroll
                for (int nt = 0; nt < 4; ++nt)
                    acc[mt][nt] = __builtin_amdgcn_mfma_f32_16x16x32_f16(
                        af[mt], bf[nt], acc[mt][nt], 0, 0, 0);
        }
        __syncthreads();
    }

#pragma unroll
    for (int mt = 0; mt < 4; ++mt) {
#pragma unroll
        for (int nt = 0; nt < 4; ++nt) {
            const int v = m0 + wm + mt * 16 + quad * 4;
            const int w = n0 + wn + nt * 16 + lane15;
#pragma unroll
            for (int r = 0; r < 4; ++r)
                Mout[(size_t)(v + r) * NODES + w] =
                    (_Float16)(acc[mt][nt][r] + ((v + r) == w ? BETA_F : 0.f));
        }
    }
}

// ---------------------------------------------------------------------------
// Hop GEMM as one flat GEMM per g:
//   D[m=v][n] = sum_w M_g[v][w] * Xt_flat[n][w],  n = chunk*256 + l,
//   N = 65536, M = 512, K = 512.
// Tile: 256(v) x 128(n), BK=64, 8 waves (4m x 2n of 64x64), 48KB LDS.
// Grid: 3072 blocks, 1-D, decoded so the 12 blocks sharing one Xt chunk
// (2 m-tiles x 2 n-halves x 3 g) occupy the SAME XCD slot (f&7):
//   f -> xcd=f&7, idx=f>>3; chunk = xcd*32 + idx/12; sub = idx%12:
//   g=sub>>2, mtile=(sub>>1)&1, half=sub&1.
__global__ __launch_bounds__(512, 4) void hop_mfma_kernel(
    const _Float16* __restrict__ M1,
    const _Float16* __restrict__ M2,
    const _Float16* __restrict__ M3,
    const _Float16* __restrict__ Xt,     // flat [n=65536][w=512]
    _Float16* __restrict__ H1,           // [chunk][v=512][l=256]
    _Float16* __restrict__ H2,
    _Float16* __restrict__ H3)
{
    __shared__ _Float16 Asl[256 * 64];   // rows m=v
    __shared__ _Float16 Bsl[128 * 64];   // rows n=(chunk,l)

    const int f    = blockIdx.x;
    const int xcd  = f & 7;
    const int idx  = f >> 3;             // 0..383
    const int chl  = idx / 12;           // 0..31
    const int sub  = idx - chl * 12;
    const int chunk = xcd * 32 + chl;    // 0..255
    const int g    = sub >> 2;           // 0..2
    const int m0   = ((sub >> 1) & 1) * 256;
    const int half = sub & 1;
    const int n0   = chunk * 256 + half * 128;
    const int l0   = half * 128;
    const size_t coff = (size_t)chunk * PLANE;

    const _Float16* __restrict__ M = (g == 0) ? M1 : (g == 1) ? M2 : M3;
    _Float16* __restrict__ H = (g == 0) ? H1 : (g == 1) ? H2 : H3;

    const int tid  = threadIdx.x;
    const int wave = tid >> 6;           // 0..7
    const int lane = tid & 63;

    const int wm = (wave >> 1) * 64;     // 0..192
    const int wn = (wave & 1) * 64;      // 0,64
    const int lane15 = lane & 15;
    const int quad = lane >> 4;
    const int srow = lane >> 3;          // staging: row within 8-row group
    const int spos = lane & 7;           // staging: 16B chunk slot

    f32x4 acc[4][4] = {};

    for (int kk = 0; kk < 8; ++kk) {
        const int k0 = kk * 64;
        const int gc = k0 + ((spos ^ srow) << 3);   // XOR-swizzled source col
        // --- stage A: 256 rows, 32 per wave (4 insts) ---
#pragma unroll
        for (int j = 0; j < 4; ++j) {
            const int r = wave * 32 + j * 8 + srow;
            gload16(M + (size_t)(m0 + r) * NODES + gc, &Asl[(wave * 32 + j * 8) * 64]);
        }
        // --- stage B: 128 rows, 16 per wave (2 insts) ---
#pragma unroll
        for (int j = 0; j < 2; ++j) {
            const int r = wave * 16 + j * 8 + srow;
            gload16(Xt + (size_t)(n0 + r) * NODES + gc, &Bsl[(wave * 16 + j * 8) * 64]);
        }
        __syncthreads();
        // --- compute ---
#pragma unroll
        for (int ks = 0; ks < 2; ++ks) {
            f16x8 af[4], bf[4];
#pragma unroll
            for (int mt = 0; mt < 4; ++mt) {
                const int m = wm + mt * 16 + lane15;
                const int pos = (ks * 4 + quad) ^ (m & 7);
                af[mt] = *(const f16x8*)&Asl[m * 64 + pos * 8];
            }
#pragma unroll
            for (int nt = 0; nt < 4; ++nt) {
                const int n = wn + nt * 16 + lane15;
                const int pos = (ks * 4 + quad) ^ (n & 7);
                bf[nt] = *(const f16x8*)&Bsl[n * 64 + pos * 8];
            }
#pragma unroll
            for (int mt = 0; mt < 4; ++mt)
#pragma unroll
                for (int nt = 0; nt < 4; ++nt)
                    acc[mt][nt] = __builtin_amdgcn_mfma_f32_16x16x32_f16(
                        af[mt], bf[nt], acc[mt][nt], 0, 0, 0);
        }
        __syncthreads();
    }

    // --- epilogue: rows v = m0+wm+mt*16+quad*4+r, cols l = l0+wn+nt*16+lane15
#pragma unroll
    for (int mt = 0; mt < 4; ++mt) {
#pragma unroll
        for (int nt = 0; nt < 4; ++nt) {
            const int v = m0 + wm + mt * 16 + quad * 4;
            const int l = l0 + wn + nt * 16 + lane15;
            const size_t base = coff + (size_t)v * SEQL + l;
#pragma unroll
            for (int r = 0; r < 4; ++r)
                H[base + (size_t)r * SEQL] = (_Float16)acc[mt][nt][r];
        }
    }
}

// ---------------------------------------------------------------------------
// out[b,o,v,l] = bias[o] + sum over 64 channel-pairs of fdot2(Hpair, Wpair).
// Groups: {Xc, H1, H2, H3}, all f16 planes.  grid: (v=512, b=8), thread = l.
// One-pass acc[64] (round-1 structure: o-split doubled FETCH, regressed).
__global__ __launch_bounds__(256) void final_kernel(
    const _Float16* __restrict__ Xc,
    const _Float16* __restrict__ H1,
    const _Float16* __restrict__ H2,
    const _Float16* __restrict__ H3,
    const unsigned int* __restrict__ Wp,
    const float* __restrict__ bias,
    float* __restrict__ out)
{
    const int v = blockIdx.x, b = blockIdx.y, l = threadIdx.x;
    const size_t vl = (size_t)v * SEQL + l;

    float acc[COUT];
#pragma unroll
    for (int o = 0; o < COUT; ++o) acc[o] = bias[o];

    const _Float16* Hs[4] = {Xc, H1, H2, H3};
#pragma unroll
    for (int g = 0; g < 4; ++g) {
        const _Float16* P = Hs[g] + (size_t)b * CIN * PLANE + vl;
        for (int cp = 0; cp < 16; ++cp) {
            const _Float16 h0 = P[(size_t)(2 * cp) * PLANE];
            const _Float16 h1 = P[(size_t)(2 * cp + 1) * PLANE];
            const f16x2 hp = {h0, h1};
            const unsigned int* wr = Wp + (g * 16 + cp) * COUT;
#pragma unroll
            for (int o = 0; o < COUT; ++o)
                acc[o] = __builtin_amdgcn_fdot2(hp, __builtin_bit_cast(f16x2, wr[o]),
                                                acc[o], false);
        }
    }
    float* O = out + (size_t)b * COUT * PLANE + vl;
#pragma unroll
    for (int o = 0; o < COUT; ++o) O[(size_t)o * PLANE] = acc[o];
}

// ---------------------------------------------------------------------------
extern "C" void kernel_launch(void* const* d_in, const int* in_sizes, int n_in,
                              void* d_out, int out_size, void* d_ws, size_t ws_size,
                              hipStream_t stream) {
    (void)in_sizes; (void)n_in; (void)out_size; (void)ws_size;
    const float* X    = (const float*)d_in[0];
    const float* A    = (const float*)d_in[1];
    const float* W    = (const float*)d_in[2];
    const float* bias = (const float*)d_in[3];
    float* out = (float*)d_out;
    char* w = (char*)d_ws;

    // ws layout (1 GiB available; we use 336 MiB)
    const size_t MB = 1ull << 20;
    unsigned int* Wp  = (unsigned int*)(w);              // 16 KB
    _Float16*     M1  = (_Float16*)(w + 1 * MB);         // 512 KB each
    _Float16*     M2  = (_Float16*)(w + 2 * MB);
    _Float16*     M3  = (_Float16*)(w + 3 * MB);
    _Float16*     Pt  = (_Float16*)(w + 4 * MB);
    _Float16*     Xt  = (_Float16*)(w + 16 * MB);        // 64 MB
    _Float16*     Xc  = (_Float16*)(w + 80 * MB);        // 64 MB
    _Float16*     Hn1 = (_Float16*)(w + 144 * MB);       // 64 MB each
    _Float16*     Hn2 = (_Float16*)(w + 208 * MB);
    _Float16*     Hn3 = (_Float16*)(w + 272 * MB);

    norm_A_kernel<<<dim3(NODES), dim3(256), 0, stream>>>(A, M1, Pt);
    prep_W_kernel<<<dim3(16), dim3(256), 0, stream>>>(W, Wp);
    prep_X_kernel<<<dim3(4, 8, 256), dim3(256), 0, stream>>>(
        X, (unsigned short*)Xt, (unsigned short*)Xc);

    // hop matrices: M2 = M1*P + beta*I ; M3 = M2*P + beta*I
    small_mm_kernel<<<dim3(4, 4), dim3(256), 0, stream>>>(M1, Pt, M2);
    small_mm_kernel<<<dim3(4, 4), dim3(256), 0, stream>>>(M2, Pt, M3);

    // three hop GEMMs fused into one 3072-block dispatch (XCD-grouped decode)
    hop_mfma_kernel<<<dim3(3072), dim3(512), 0, stream>>>(
        M1, M2, M3, Xt, Hn1, Hn2, Hn3);

    final_kernel<<<dim3(NODES, NB), dim3(256), 0, stream>>>(
        Xc, Hn1, Hn2, Hn3, Wp, bias, out);
}